// Round 4
// baseline (771.319 us; speedup 1.0000x reference)
//
#include <hip/hip_runtime.h>

#define CAP 32
#define K 16   // steps per batch; obuf = 2 sets * 2 buf * K * 3 * 64 * 4B = 96 KiB

// ---------------------------------------------------------------------------
// Kernel 1: runtime sparsification of W1 (general; for this input nnz=1/row).
// ---------------------------------------------------------------------------
__global__ void sparsify_kernel(const float* __restrict__ W1, int N,
                                int* __restrict__ cnts, int* __restrict__ cols,
                                float* __restrict__ wts) {
  __shared__ int scnt;
  const int row = blockIdx.x;
  if (threadIdx.x == 0) scnt = 0;
  __syncthreads();
  const float* wr = W1 + (long)row * N;
  for (int k = threadIdx.x; k < N; k += blockDim.x) {
    float w = wr[k];
    if (w != 0.0f) {
      int slot = atomicAdd(&scnt, 1);
      if (slot < CAP) {
        cols[row * CAP + slot] = k;
        wts[row * CAP + slot] = w;
      }
    }
  }
  __syncthreads();
  if (threadIdx.x == 0) {
    cnts[row] = scnt;
    if (scnt == 0) { cols[row * CAP] = 0; wts[row * CAP] = 0.0f; }
  }
}

// ---------------------------------------------------------------------------
// Kernel 2: warm input_batch into LLC so compute-wave prefetch loads retire
// well before consumption.
// ---------------------------------------------------------------------------
__global__ void touch_kernel(const float4* __restrict__ x4, long n4,
                             float* __restrict__ dump) {
  long i = (long)blockIdx.x * blockDim.x + threadIdx.x;
  const long stride = (long)gridDim.x * blockDim.x;
  float acc = 0.f;
  for (; i < n4; i += stride) {
    float4 v = x4[i];
    acc += v.x + v.y + v.z + v.w;
  }
  if (acc == 1234.56789f) dump[blockIdx.x & 1023] = acc;  // defeat DCE
}

// ---------------------------------------------------------------------------
// One Izhikevich step, bitwise numpy op order (contract off at kernel scope).
// ---------------------------------------------------------------------------
#define IZH_STEP(xv, sout)                        \
  {                                               \
    const float I = w0 * (xv);                    \
    float t1 = 0.04f * v;                         \
    float t2 = t1 * v;                            \
    float t3 = 5.0f * v;                          \
    float t4 = t2 + t3;                           \
    float t5 = t4 + 140.0f;                       \
    float t6 = t5 - u;                            \
    float t7 = t6 + I;                            \
    float vn = v + t7;      /* dt==1: exact */    \
    float q1 = bn * v;                            \
    float q2 = q1 - u;                            \
    float q3 = Pn * q2;                           \
    float un = u + q3;                            \
    float df = vn - thn;                          \
    bool sp = df > 0.0f;                          \
    v = sp ? cn : vn;       /* == vn*(1-s)+c*s */ \
    u = un + (sp ? dn : 0.0f); /* == un + d*s */  \
    sout = sp ? 1.0f : 0.0f;                      \
  }

// ---------------------------------------------------------------------------
// Kernel 3: producer/consumer, TWO compute waves per SIMD.
//   All 1-compute-wave-per-SIMD variants measured ~120-127 cyc/step with the
//   VALU issuing only ~40% of cycles: a solo wave cannot fill its SIMD's
//   issue slots (per-wave cadence + ~12-op dependent chain, zero TLP).
//   Fix: 8 blocks x 512 thr. Waves with wid%4==0 (w0,w4 -> SAME SIMD under
//   round-robin wid%4 mapping) are compute waves, each owning 64 neurons;
//   their streams interleave so each fills the other's stall slots.
//   Waves w1-3 / w5-7: s/v/u writers per set (stores never on compute waves
//   -- R1/R2 showed in-order store retirement poisons the compute wave's
//   load waits). Sync = raw s_barrier + lgkmcnt(0) only (no vmcnt drain).
// ---------------------------------------------------------------------------
__global__ void __launch_bounds__(512) izh_pc2_kernel(
    const float* __restrict__ X, const float* __restrict__ state,
    const float* __restrict__ a, const float* __restrict__ b,
    const float* __restrict__ c, const float* __restrict__ d,
    const float* __restrict__ th, const float* __restrict__ dtv,
    const float* __restrict__ W1,
    const int* __restrict__ cnts, const int* __restrict__ cols,
    const float* __restrict__ wts,
    float* __restrict__ o_s, float* __restrict__ o_st,
    int T, int N)
{
#pragma clang fp contract(off)
  __shared__ float obuf[2][2][K][3][64];  // [set][buf][step][s,v,u][lane]
  __shared__ int s_ok[2];

  const int wid  = threadIdx.x >> 6;
  const int lane = threadIdx.x & 63;
  const int role = wid & 3;               // 0: compute, 1/2/3: s/v/u writer
  const int set  = wid >> 2;              // 0: w0-w3, 1: w4-w7
  const int base = blockIdx.x * 128 + set * 64;
  const int gn   = base + lane;
  const long N2  = 2L * N;
  const int B    = T / K;

  // ---- block-uniform path decision (one ballot per compute wave) ----
  if (role == 0) {
    bool elig = (base + 64 <= N);
    if (elig) elig = (cnts[gn] == 1) && (dtv[gn] == 1.0f);
    unsigned long long m = __ballot(elig);
    if (lane == 0) s_ok[set] = (m == ~0ULL) ? 1 : 0;
  }
  __syncthreads();
  const bool fast = (s_ok[0] != 0) && (s_ok[1] != 0);

  if (fast) {
    if (role == 0) {
      // ================= compute wave (one per set) =================
      __builtin_amdgcn_s_setprio(1);
      float v = state[gn], u = state[N + gn];
      const float bn = b[gn], cn = c[gn], dn = d[gn], thn = th[gn];
      const float Pn = dtv[gn] * a[gn];   // same operands/order as ref's dt*a
      const float w0 = wts[gn * CAP];
      const int   c0 = cols[gn * CAP];
      const float* Xp = X + c0;

      float xA[K], xB[K];
      if (B >= 1) {
#pragma unroll
        for (int i = 0; i < K; ++i) xA[i] = Xp[(size_t)i * N];
      }

      // one batch: K steps from reg buffer XR into obuf[set][bsel].
      // lgkmcnt(0) flushes the ds_writes; NO vmcnt wait is emitted.
#define COMPUTE(XR, bsel)                                      \
      {                                                        \
        _Pragma("unroll")                                      \
        for (int i = 0; i < K; ++i) {                          \
          float s_;                                            \
          IZH_STEP(XR[i], s_);                                 \
          obuf[set][bsel][i][0][lane] = s_;                    \
          obuf[set][bsel][i][1][lane] = v;                     \
          obuf[set][bsel][i][2][lane] = u;                     \
        }                                                      \
        asm volatile("s_waitcnt lgkmcnt(0)" ::: "memory");     \
        __builtin_amdgcn_s_barrier();                          \
      }

      int k = 0;
      for (; k + 1 < B; k += 2) {
        // prefetch batch k+1 while computing batch k
#pragma unroll
        for (int i = 0; i < K; ++i)
          xB[i] = Xp[(size_t)((k + 1) * K + i) * N];
        COMPUTE(xA, 0)
        // prefetch batch k+2 while computing batch k+1
        if (k + 2 < B) {
#pragma unroll
          for (int i = 0; i < K; ++i)
            xA[i] = Xp[(size_t)((k + 2) * K + i) * N];
        }
        COMPUTE(xB, 1)
      }
      if (k < B) COMPUTE(xA, 0)           // odd-B leftover (bsel = k&1 = 0)
#undef COMPUTE
      __builtin_amdgcn_s_setprio(0);

      // tail (T % K != 0): direct global stores (none for T=8192,K=16)
      for (int t = B * K; t < T; ++t) {
        float s_;
        IZH_STEP(Xp[(size_t)t * N], s_);
        o_s[(long)t * N + gn] = s_;
        o_st[(long)t * N2 + gn] = v;
        o_st[(long)t * N2 + N + gn] = u;
      }
    } else {
      // ================= writer waves =================
      const int cidx = role - 1;          // 0:s 1:v 2:u
      float* P; long RS;
      if (role == 1)      { P = o_s;      RS = N;  }
      else if (role == 2) { P = o_st;     RS = N2; }
      else                { P = o_st + N; RS = N2; }
      const int r = lane >> 4, j = lane & 15;

      for (int k = 0; k < B; ++k) {
        if (k > 0) {
          const int q = k - 1, bsel = q & 1, t0 = q * K;
#pragma unroll
          for (int i = 0; i < K; i += 4) {
            float4 val = *(const float4*)&obuf[set][bsel][i + r][cidx][4 * j];
            *(float4*)(P + (size_t)(t0 + i + r) * RS + base + 4 * j) = val;
          }
        }
        __builtin_amdgcn_s_barrier();     // raw: stores stay in flight
      }
      if (B > 0) {                        // drain last staged batch
        const int q = B - 1, bsel = q & 1, t0 = q * K;
#pragma unroll
        for (int i = 0; i < K; i += 4) {
          float4 val = *(const float4*)&obuf[set][bsel][i + r][cidx][4 * j];
          *(float4*)(P + (size_t)(t0 + i + r) * RS + base + 4 * j) = val;
        }
      }
    }
  } else {
    // ---- general fallback: compute-role threads only, any cnt / dt ----
    if (role != 0 || gn >= N) return;
    float v = state[gn], u = state[N + gn];
    const float an = a[gn], bn = b[gn], cn = c[gn], dn = d[gn];
    const float thn = th[gn], dtn = dtv[gn];
    const float Pn = dtn * an;
    const int cnt = cnts[gn];
    for (int t = 0; t < T; ++t) {
      float I = 0.0f;
      if (cnt <= CAP) {
        for (int j = 0; j < cnt; ++j)
          I = I + wts[gn * CAP + j] * X[(size_t)t * N + cols[gn * CAP + j]];
      } else {
        const float* wr = W1 + (size_t)gn * N;
        const float* xr = X + (size_t)t * N;
        for (int kk = 0; kk < N; ++kk) I = I + wr[kk] * xr[kk];
      }
      float t1 = 0.04f * v; float t2 = t1 * v; float t3 = 5.0f * v;
      float t4 = t2 + t3; float t5 = t4 + 140.0f; float t6 = t5 - u;
      float t7 = t6 + I; float t8 = dtn * t7; float vn = v + t8;
      float q1 = bn * v; float q2 = q1 - u; float q3 = Pn * q2; float un = u + q3;
      float df = vn - thn; bool sp = df > 0.0f;
      v = sp ? cn : vn; u = un + (sp ? dn : 0.0f);
      o_s[(size_t)t * N + gn] = sp ? 1.0f : 0.0f;
      o_st[(size_t)t * N2 + gn] = v;
      o_st[(size_t)t * N2 + N + gn] = u;
    }
  }
}

// ---------------------------------------------------------------------------
// Kernel 4: r[t] = W2 @ s[t]  (exact: terms are 20*{0,1}, sums < 2^24)
// ---------------------------------------------------------------------------
__global__ void decode_dot_kernel(const float* __restrict__ o_s,
                                  const float* __restrict__ W2,
                                  float* __restrict__ r, int N) {
  const int t = blockIdx.x;
  const float* srow = o_s + (long)t * N;
  float p = 0.0f;
  for (int n = threadIdx.x; n < N; n += blockDim.x)
    p += W2[n] * srow[n];
  for (int off = 32; off > 0; off >>= 1) p += __shfl_down(p, off);
  __shared__ float red[4];
  if ((threadIdx.x & 63) == 0) red[threadIdx.x >> 6] = p;
  __syncthreads();
  if (threadIdx.x == 0) {
    float tot = 0.f;
    const int nw = blockDim.x >> 6;
    for (int w = 0; w < nw; ++w) tot += red[w];
    r[t] = tot;
  }
}

// ---------------------------------------------------------------------------
// Kernel 5: dm[t] = leak*dm[t-1] + r[t], chunked affine scan (1 block, 64 thr)
// ---------------------------------------------------------------------------
__global__ void decode_scan_kernel(const float* __restrict__ r,
                                   const float* __restrict__ leakp,
                                   float* __restrict__ out, int T) {
  __shared__ float Bsh[64], Ssh[64];
  const float leakv = leakp[0];
  const int i = threadIdx.x;                 // 0..63
  const int chunk = (T + 63) / 64;
  const int t0 = i * chunk;
  float B = 0.0f;
  for (int j = 0; j < chunk; ++j) {
    int t = t0 + j;
    if (t < T) B = leakv * B + r[t];
  }
  Bsh[i] = B;
  float A = 1.0f, p = leakv; int e = chunk;
  while (e) { if (e & 1) A *= p; p *= p; e >>= 1; }
  __syncthreads();
  if (i == 0) {
    float dm = 0.0f;
    for (int k = 0; k < 64; ++k) { Ssh[k] = dm; dm = A * dm + Bsh[k]; }
  }
  __syncthreads();
  float dm = Ssh[i];
  for (int j = 0; j < chunk; ++j) {
    int t = t0 + j;
    if (t < T) { dm = leakv * dm + r[t]; out[t] = dm; }
  }
}

// ---------------------------------------------------------------------------
extern "C" void kernel_launch(void* const* d_in, const int* in_sizes, int n_in,
                              void* d_out, int out_size, void* d_ws, size_t ws_size,
                              hipStream_t stream) {
  const float* X  = (const float*)d_in[0];
  const float* st = (const float*)d_in[1];
  const float* W1 = (const float*)d_in[2];
  const float* W2 = (const float*)d_in[3];
  const float* a  = (const float*)d_in[4];
  const float* b  = (const float*)d_in[5];
  const float* c  = (const float*)d_in[6];
  const float* d  = (const float*)d_in[7];
  const float* th = (const float*)d_in[8];
  const float* dt = (const float*)d_in[9];
  const float* lk = (const float*)d_in[10];
  const int N = in_sizes[4];          // a has N elements
  const int T = in_sizes[0] / N;

  float* o_s  = (float*)d_out;               // outputs  [T,N]
  float* o_st = o_s + (long)T * N;           // states   [T,2,N]
  float* o_dm = o_st + 2L * (long)T * N;     // decoded  [T,1]

  int*   cnts = (int*)d_ws;                  // N
  int*   cols = cnts + N;                    // N*CAP
  float* wts  = (float*)(cols + (long)N * CAP); // N*CAP
  float* rbuf = wts + (long)N * CAP;         // T
  float* dump = rbuf + T;                    // toucher sink

  sparsify_kernel<<<N, 256, 0, stream>>>(W1, N, cnts, cols, wts);
  const long n4 = ((long)T * N) / 4;
  touch_kernel<<<1024, 256, 0, stream>>>((const float4*)X, n4, dump);
  const int nblk = (N + 127) / 128;
  izh_pc2_kernel<<<nblk, 512, 0, stream>>>(X, st, a, b, c, d, th, dt, W1,
                                           cnts, cols, wts, o_s, o_st, T, N);
  decode_dot_kernel<<<T, 256, 0, stream>>>(o_s, W2, rbuf, N);
  decode_scan_kernel<<<1, 64, 0, stream>>>(rbuf, lk, o_dm, T);
}

// Round 5
// 513.243 us; speedup vs baseline: 1.5028x; 1.5028x over previous
//
#include <hip/hip_runtime.h>

#define CAP 32
#define K 32   // steps per batch; ibuf 16KB + obuf 32KB = 48KB LDS

// ---------------------------------------------------------------------------
// Kernel 1: runtime sparsification of W1 (general; for this input nnz=1/row).
// ---------------------------------------------------------------------------
__global__ void sparsify_kernel(const float* __restrict__ W1, int N,
                                int* __restrict__ cnts, int* __restrict__ cols,
                                float* __restrict__ wts) {
  __shared__ int scnt;
  const int row = blockIdx.x;
  if (threadIdx.x == 0) scnt = 0;
  __syncthreads();
  const float* wr = W1 + (long)row * N;
  for (int k = threadIdx.x; k < N; k += blockDim.x) {
    float w = wr[k];
    if (w != 0.0f) {
      int slot = atomicAdd(&scnt, 1);
      if (slot < CAP) {
        cols[row * CAP + slot] = k;
        wts[row * CAP + slot] = w;
      }
    }
  }
  __syncthreads();
  if (threadIdx.x == 0) {
    cnts[row] = scnt;
    if (scnt == 0) { cols[row * CAP] = 0; wts[row * CAP] = 0.0f; }
  }
}

// ---------------------------------------------------------------------------
// Kernel 2: warm input_batch into LLC so the loader's loads retire fast.
// ---------------------------------------------------------------------------
__global__ void touch_kernel(const float4* __restrict__ x4, long n4,
                             float* __restrict__ dump) {
  long i = (long)blockIdx.x * blockDim.x + threadIdx.x;
  const long stride = (long)gridDim.x * blockDim.x;
  float acc = 0.f;
  for (; i < n4; i += stride) {
    float4 v = x4[i];
    acc += v.x + v.y + v.z + v.w;
  }
  if (acc == 1234.56789f) dump[blockIdx.x & 1023] = acc;  // defeat DCE
}

// ---------------------------------------------------------------------------
// Kernel 3: producer/consumer, MINIMAL-INSTRUCTION compute wave.
//   Empirical law from 5 experiments: the critical wave retires ~4-5 cyc per
//   instruction regardless of sync structure / store placement / co-residency
//   (VALUBusy across R1/R3/R4 matches a 4 cyc/inst issue-cadence model to
//   within 5%). So: minimize instructions per step on the compute wave.
//     wave0 (compute): 16 VALU + 1 ds_read (I) + 2 ds_write (vn,un) = 19/step.
//       - I = w*x precomputed by the loader, read via imm-offset ds_read.
//       - Writes PRE-reset vn and PRE-jump un; writers re-derive the spike.
//       - sp = (vn > thn) is bitwise-equivalent to ((vn-thn) > 0) in IEEE.
//     wave1 (loader + s-writer): loads x, computes I=w*x -> ibuf (dbuf,
//       one batch ahead); recomputes s = sp?1:0 from obuf.vn and stores.
//     wave2 (v-writer): v_out = sp ? c : vn.   wave3 (u-writer): un + sp?d:0.
//   Sync = raw s_barrier + lgkmcnt(0) only; writer stores stay in flight.
// ---------------------------------------------------------------------------
__global__ void __launch_bounds__(256) izh_pc3_kernel(
    const float* __restrict__ X, const float* __restrict__ state,
    const float* __restrict__ a, const float* __restrict__ b,
    const float* __restrict__ c, const float* __restrict__ d,
    const float* __restrict__ th, const float* __restrict__ dtv,
    const float* __restrict__ W1,
    const int* __restrict__ cnts, const int* __restrict__ cols,
    const float* __restrict__ wts,
    float* __restrict__ o_s, float* __restrict__ o_st,
    int T, int N)
{
#pragma clang fp contract(off)
  __shared__ float ibuf[2][K][64];        // staged I = w*x   (16 KB)
  __shared__ float obuf[2][K][2][64];     // staged vn,un     (32 KB)
  __shared__ int s_fast;

  const int wid  = threadIdx.x >> 6;
  const int lane = threadIdx.x & 63;
  const int base = blockIdx.x * 64;
  const int gn   = base + lane;
  const long N2  = 2L * N;
  const int B    = T / K;

  // ---- block-uniform path decision ----
  if (wid == 0) {
    bool elig = (base + 64 <= N);
    if (elig) elig = (cnts[gn] == 1) && (dtv[gn] == 1.0f);
    unsigned long long m = __ballot(elig);
    if (lane == 0) s_fast = (m == ~0ULL) ? 1 : 0;
  }
  __syncthreads();

  if (s_fast) {
    // ---- prologue: loader fills ibuf[0] (batch 0) ----
    if (wid == 1) {
      const float wn = wts[gn * CAP];
      const int   c0 = cols[gn * CAP];
      const float* Xp = X + c0;
      float xr[K];
#pragma unroll
      for (int i = 0; i < K; ++i) xr[i] = Xp[(size_t)i * N];
#pragma unroll
      for (int i = 0; i < K; ++i) ibuf[0][i][lane] = wn * xr[i];
    }
    __syncthreads();   // one-time full sync (vmcnt drain OK outside loop)

    if (wid == 0) {
      // ================= compute wave =================
      float v = state[gn], u = state[N + gn];
      const float bn = b[gn], cn = c[gn], dn = d[gn], thn = th[gn];
      const float Pn = dtv[gn] * a[gn];   // same operands/order as ref's dt*a

      for (int k = 0; k < B; ++k) {
        const int bsel = k & 1;
#pragma unroll
        for (int i = 0; i < K; ++i) {
          const float I = ibuf[bsel][i][lane];     // 1 ds_read, imm offset
          float t1 = 0.04f * v;
          float t2 = t1 * v;
          float t3 = 5.0f * v;
          float t4 = t2 + t3;
          float t5 = t4 + 140.0f;
          float t6 = t5 - u;
          float t7 = t6 + I;
          float vn = v + t7;      /* dt==1: exact */
          float q1 = bn * v;
          float q2 = q1 - u;
          float q3 = Pn * q2;
          float un = u + q3;
          obuf[bsel][i][0][lane] = vn;             // pre-reset v
          obuf[bsel][i][1][lane] = un;             // pre-jump u
          bool sp = vn > thn;     /* == (vn-thn)>0 bitwise (IEEE) */
          v = sp ? cn : vn;
          u = un + (sp ? dn : 0.0f);
        }
        asm volatile("s_waitcnt lgkmcnt(0)" ::: "memory");
        __builtin_amdgcn_s_barrier();
      }

      // tail (T % K != 0): direct global path (none for T=8192,K=32)
      if (B * K < T) {
        const float w0 = wts[gn * CAP];
        const float* Xp = X + cols[gn * CAP];
        for (int t = B * K; t < T; ++t) {
          const float I = w0 * Xp[(size_t)t * N];
          float t1 = 0.04f * v; float t2 = t1 * v; float t3 = 5.0f * v;
          float t4 = t2 + t3; float t5 = t4 + 140.0f; float t6 = t5 - u;
          float t7 = t6 + I; float vn = v + t7;
          float q1 = bn * v; float q2 = q1 - u; float q3 = Pn * q2;
          float un = u + q3;
          bool sp = vn > thn;
          v = sp ? cn : vn; u = un + (sp ? dn : 0.0f);
          o_s[(long)t * N + gn] = sp ? 1.0f : 0.0f;
          o_st[(long)t * N2 + gn] = v;
          o_st[(long)t * N2 + N + gn] = u;
        }
      }
    } else if (wid == 1) {
      // ================= loader + s-writer =================
      const float wn = wts[gn * CAP];
      const int   c0 = cols[gn * CAP];
      const float* Xp = X + c0;
      const int r = lane >> 4, j = lane & 15;
      const float4 th4 = *(const float4*)&th[base + 4 * j];

      for (int k = 0; k < B; ++k) {
        if (k + 1 < B) {                    // stage I for batch k+1
          float xr[K];
#pragma unroll
          for (int i = 0; i < K; ++i) xr[i] = Xp[(size_t)((k + 1) * K + i) * N];
#pragma unroll
          for (int i = 0; i < K; ++i) ibuf[(k + 1) & 1][i][lane] = wn * xr[i];
        }
        if (k > 0) {                        // s-store batch k-1
          const int q = k - 1, bsel = q & 1, t0 = q * K;
#pragma unroll
          for (int i = 0; i < K; i += 4) {
            float4 vn4 = *(const float4*)&obuf[bsel][i + r][0][4 * j];
            float4 s4;
            s4.x = vn4.x > th4.x ? 1.0f : 0.0f;
            s4.y = vn4.y > th4.y ? 1.0f : 0.0f;
            s4.z = vn4.z > th4.z ? 1.0f : 0.0f;
            s4.w = vn4.w > th4.w ? 1.0f : 0.0f;
            *(float4*)(o_s + (size_t)(t0 + i + r) * N + base + 4 * j) = s4;
          }
        }
        asm volatile("s_waitcnt lgkmcnt(0)" ::: "memory");
        __builtin_amdgcn_s_barrier();
      }
      if (B > 0) {                          // drain s for batch B-1
        const int q = B - 1, bsel = q & 1, t0 = q * K;
#pragma unroll
        for (int i = 0; i < K; i += 4) {
          float4 vn4 = *(const float4*)&obuf[bsel][i + r][0][4 * j];
          float4 s4;
          s4.x = vn4.x > th4.x ? 1.0f : 0.0f;
          s4.y = vn4.y > th4.y ? 1.0f : 0.0f;
          s4.z = vn4.z > th4.z ? 1.0f : 0.0f;
          s4.w = vn4.w > th4.w ? 1.0f : 0.0f;
          *(float4*)(o_s + (size_t)(t0 + i + r) * N + base + 4 * j) = s4;
        }
      }
    } else if (wid == 2) {
      // ================= v-writer: v_out = sp ? c : vn =================
      const int r = lane >> 4, j = lane & 15;
      const float4 th4 = *(const float4*)&th[base + 4 * j];
      const float4 c4  = *(const float4*)&c[base + 4 * j];

      for (int k = 0; k < B; ++k) {
        if (k > 0) {
          const int q = k - 1, bsel = q & 1, t0 = q * K;
#pragma unroll
          for (int i = 0; i < K; i += 4) {
            float4 vn4 = *(const float4*)&obuf[bsel][i + r][0][4 * j];
            float4 o4;
            o4.x = vn4.x > th4.x ? c4.x : vn4.x;
            o4.y = vn4.y > th4.y ? c4.y : vn4.y;
            o4.z = vn4.z > th4.z ? c4.z : vn4.z;
            o4.w = vn4.w > th4.w ? c4.w : vn4.w;
            *(float4*)(o_st + (size_t)(t0 + i + r) * N2 + base + 4 * j) = o4;
          }
        }
        __builtin_amdgcn_s_barrier();
      }
      if (B > 0) {
        const int q = B - 1, bsel = q & 1, t0 = q * K;
#pragma unroll
        for (int i = 0; i < K; i += 4) {
          float4 vn4 = *(const float4*)&obuf[bsel][i + r][0][4 * j];
          float4 o4;
          o4.x = vn4.x > th4.x ? c4.x : vn4.x;
          o4.y = vn4.y > th4.y ? c4.y : vn4.y;
          o4.z = vn4.z > th4.z ? c4.z : vn4.z;
          o4.w = vn4.w > th4.w ? c4.w : vn4.w;
          *(float4*)(o_st + (size_t)(t0 + i + r) * N2 + base + 4 * j) = o4;
        }
      }
    } else {
      // ================= u-writer: u_out = un + (sp ? d : 0) =============
      const int r = lane >> 4, j = lane & 15;
      const float4 th4 = *(const float4*)&th[base + 4 * j];
      const float4 d4  = *(const float4*)&d[base + 4 * j];

      for (int k = 0; k < B; ++k) {
        if (k > 0) {
          const int q = k - 1, bsel = q & 1, t0 = q * K;
#pragma unroll
          for (int i = 0; i < K; i += 4) {
            float4 vn4 = *(const float4*)&obuf[bsel][i + r][0][4 * j];
            float4 un4 = *(const float4*)&obuf[bsel][i + r][1][4 * j];
            float4 o4;
            o4.x = un4.x + (vn4.x > th4.x ? d4.x : 0.0f);
            o4.y = un4.y + (vn4.y > th4.y ? d4.y : 0.0f);
            o4.z = un4.z + (vn4.z > th4.z ? d4.z : 0.0f);
            o4.w = un4.w + (vn4.w > th4.w ? d4.w : 0.0f);
            *(float4*)(o_st + (size_t)(t0 + i + r) * N2 + N + base + 4 * j) = o4;
          }
        }
        __builtin_amdgcn_s_barrier();
      }
      if (B > 0) {
        const int q = B - 1, bsel = q & 1, t0 = q * K;
#pragma unroll
        for (int i = 0; i < K; i += 4) {
          float4 vn4 = *(const float4*)&obuf[bsel][i + r][0][4 * j];
          float4 un4 = *(const float4*)&obuf[bsel][i + r][1][4 * j];
          float4 o4;
          o4.x = un4.x + (vn4.x > th4.x ? d4.x : 0.0f);
          o4.y = un4.y + (vn4.y > th4.y ? d4.y : 0.0f);
          o4.z = un4.z + (vn4.z > th4.z ? d4.z : 0.0f);
          o4.w = un4.w + (vn4.w > th4.w ? d4.w : 0.0f);
          *(float4*)(o_st + (size_t)(t0 + i + r) * N2 + N + base + 4 * j) = o4;
        }
      }
    }
  } else {
    // ---- general fallback: wave0 threads only, any cnt / dt ----
    if (wid != 0 || gn >= N) return;
    float v = state[gn], u = state[N + gn];
    const float an = a[gn], bn = b[gn], cn = c[gn], dn = d[gn];
    const float thn = th[gn], dtn = dtv[gn];
    const float Pn = dtn * an;
    const int cnt = cnts[gn];
    for (int t = 0; t < T; ++t) {
      float I = 0.0f;
      if (cnt <= CAP) {
        for (int j = 0; j < cnt; ++j)
          I = I + wts[gn * CAP + j] * X[(size_t)t * N + cols[gn * CAP + j]];
      } else {
        const float* wr = W1 + (size_t)gn * N;
        const float* xr = X + (size_t)t * N;
        for (int kk = 0; kk < N; ++kk) I = I + wr[kk] * xr[kk];
      }
      float t1 = 0.04f * v; float t2 = t1 * v; float t3 = 5.0f * v;
      float t4 = t2 + t3; float t5 = t4 + 140.0f; float t6 = t5 - u;
      float t7 = t6 + I; float t8 = dtn * t7; float vn = v + t8;
      float q1 = bn * v; float q2 = q1 - u; float q3 = Pn * q2; float un = u + q3;
      float df = vn - thn; bool sp = df > 0.0f;
      v = sp ? cn : vn; u = un + (sp ? dn : 0.0f);
      o_s[(size_t)t * N + gn] = sp ? 1.0f : 0.0f;
      o_st[(size_t)t * N2 + gn] = v;
      o_st[(size_t)t * N2 + N + gn] = u;
    }
  }
}

// ---------------------------------------------------------------------------
// Kernel 4: r[t] = W2 @ s[t]  (exact: terms are 20*{0,1}, sums < 2^24)
// ---------------------------------------------------------------------------
__global__ void decode_dot_kernel(const float* __restrict__ o_s,
                                  const float* __restrict__ W2,
                                  float* __restrict__ r, int N) {
  const int t = blockIdx.x;
  const float* srow = o_s + (long)t * N;
  float p = 0.0f;
  for (int n = threadIdx.x; n < N; n += blockDim.x)
    p += W2[n] * srow[n];
  for (int off = 32; off > 0; off >>= 1) p += __shfl_down(p, off);
  __shared__ float red[4];
  if ((threadIdx.x & 63) == 0) red[threadIdx.x >> 6] = p;
  __syncthreads();
  if (threadIdx.x == 0) {
    float tot = 0.f;
    const int nw = blockDim.x >> 6;
    for (int w = 0; w < nw; ++w) tot += red[w];
    r[t] = tot;
  }
}

// ---------------------------------------------------------------------------
// Kernel 5: dm[t] = leak*dm[t-1] + r[t], chunked affine scan (1 block, 64 thr)
// ---------------------------------------------------------------------------
__global__ void decode_scan_kernel(const float* __restrict__ r,
                                   const float* __restrict__ leakp,
                                   float* __restrict__ out, int T) {
  __shared__ float Bsh[64], Ssh[64];
  const float leakv = leakp[0];
  const int i = threadIdx.x;                 // 0..63
  const int chunk = (T + 63) / 64;
  const int t0 = i * chunk;
  float B = 0.0f;
  for (int j = 0; j < chunk; ++j) {
    int t = t0 + j;
    if (t < T) B = leakv * B + r[t];
  }
  Bsh[i] = B;
  float A = 1.0f, p = leakv; int e = chunk;
  while (e) { if (e & 1) A *= p; p *= p; e >>= 1; }
  __syncthreads();
  if (i == 0) {
    float dm = 0.0f;
    for (int k = 0; k < 64; ++k) { Ssh[k] = dm; dm = A * dm + Bsh[k]; }
  }
  __syncthreads();
  float dm = Ssh[i];
  for (int j = 0; j < chunk; ++j) {
    int t = t0 + j;
    if (t < T) { dm = leakv * dm + r[t]; out[t] = dm; }
  }
}

// ---------------------------------------------------------------------------
extern "C" void kernel_launch(void* const* d_in, const int* in_sizes, int n_in,
                              void* d_out, int out_size, void* d_ws, size_t ws_size,
                              hipStream_t stream) {
  const float* X  = (const float*)d_in[0];
  const float* st = (const float*)d_in[1];
  const float* W1 = (const float*)d_in[2];
  const float* W2 = (const float*)d_in[3];
  const float* a  = (const float*)d_in[4];
  const float* b  = (const float*)d_in[5];
  const float* c  = (const float*)d_in[6];
  const float* d  = (const float*)d_in[7];
  const float* th = (const float*)d_in[8];
  const float* dt = (const float*)d_in[9];
  const float* lk = (const float*)d_in[10];
  const int N = in_sizes[4];          // a has N elements
  const int T = in_sizes[0] / N;

  float* o_s  = (float*)d_out;               // outputs  [T,N]
  float* o_st = o_s + (long)T * N;           // states   [T,2,N]
  float* o_dm = o_st + 2L * (long)T * N;     // decoded  [T,1]

  int*   cnts = (int*)d_ws;                  // N
  int*   cols = cnts + N;                    // N*CAP
  float* wts  = (float*)(cols + (long)N * CAP); // N*CAP
  float* rbuf = wts + (long)N * CAP;         // T
  float* dump = rbuf + T;                    // toucher sink

  sparsify_kernel<<<N, 256, 0, stream>>>(W1, N, cnts, cols, wts);
  const long n4 = ((long)T * N) / 4;
  touch_kernel<<<1024, 256, 0, stream>>>((const float4*)X, n4, dump);
  const int nblk = (N + 63) / 64;
  izh_pc3_kernel<<<nblk, 256, 0, stream>>>(X, st, a, b, c, d, th, dt, W1,
                                           cnts, cols, wts, o_s, o_st, T, N);
  decode_dot_kernel<<<T, 256, 0, stream>>>(o_s, W2, rbuf, N);
  decode_scan_kernel<<<1, 64, 0, stream>>>(rbuf, lk, o_dm, T);
}